// Round 15
// baseline (70.772 us; speedup 1.0000x reference)
//
#include <hip/hip_runtime.h>
#include <cmath>

#define Bn 32
#define Hn 512
#define Wn 512
#define PADn 4
#define TW 32
#define TH 32
#define RH 40
#define RW 40
#define PS 42          // av plane stride (float2): even -> b128-aligned reads
#define FS 42          // f plane stride (floats)
#define HS 33          // hb/hg stride (float2)
#define QS 33          // hqd stride (floats): bank = (row+cx)%32 -> 2-way free
#define NPTS (RH * RW)            // 1600
#define NTILES 8192
#define NBLK 1024
#define TPT (NTILES / NBLK)       // 8

struct GaussW { float g[9]; };

// B task: 4 adjacent h-cols. Output 20 floats: [m]{hb_i,hb_v,hg_i,hg_v,hqd}.
__device__ __forceinline__ void do_task(
    int task, const GaussW& gw, const float2* s_av, const float* s_f,
    float* out)
{
    int ry = task >> 3, g = task & 7;
    int po = ry * PS + 4 * g;
    float2 av[12];
    #pragma unroll
    for (int j = 0; j < 6; ++j)
        *(float4*)&av[2 * j] = *(const float4*)&s_av[po + 2 * j];

    float bx[4] = {0,0,0,0}, by[4] = {0,0,0,0};
    float pd[12];
    const float2* fp = (const float2*)s_f;
    int fo2 = (ry * FS + 4 * g) >> 1;          // FS even, 4g even
    #pragma unroll
    for (int j = 0; j < 6; ++j) {
        float2 w = fp[fo2 + j];
        #pragma unroll
        for (int e = 0; e < 2; ++e) {
            int k = 2 * j + e;
            float a = av[k].x, v = av[k].y, f = e ? w.y : w.x;
            float di = a - f, dv = v - f;
            float d2i = di * di, d2v = dv * dv;
            #pragma unroll
            for (int m = 0; m < 4; ++m)
                if (k - m >= 0 && k - m <= 8) { bx[m] += d2i; by[m] += d2v; }
            pd[k] = (a - v) * (a + v);         // a^2 - v^2
        }
    }
    #pragma unroll
    for (int m = 0; m < 4; ++m) {
        float ga = 0.f, gv = 0.f, qd = 0.f;
        #pragma unroll
        for (int dx = 0; dx < 9; ++dx) {
            float gg = gw.g[dx];
            ga = fmaf(gg, av[m + dx].x, ga);
            gv = fmaf(gg, av[m + dx].y, gv);
            qd = fmaf(gg, pd[m + dx], qd);
        }
        out[5*m+0] = bx[m]; out[5*m+1] = by[m];
        out[5*m+2] = ga;    out[5*m+3] = gv;   out[5*m+4] = qd;
    }
}

__device__ __forceinline__ void write_task(
    int task, const float* out, float2* s_hb, float2* s_hg, float* s_hqd)
{
    int ry = task >> 3, g = task & 7;
    int ho = ry * HS + 4 * g;
    int qo = ry * QS + 4 * g;
    #pragma unroll
    for (int m = 0; m < 4; ++m) {
        s_hb[ho + m]  = make_float2(out[5*m+0], out[5*m+1]);
        s_hg[ho + m]  = make_float2(out[5*m+2], out[5*m+3]);
        s_hqd[qo + m] = out[5*m+4];
    }
}

// R15: union-aliased LDS (B holds h in regs across a barrier, then writes h
// OVER the planes) + single-float hqd plane (linearity of vertical conv).
// LDS = max(planes 20160, h 26400) = 26400 B -> cap 6 blocks/CU (VGPR will
// bind at 4-5). 4 barriers/tile, paid for by residency. No launch_bounds
// arg2 (R4/R10/R11: it only ever caused spills).
__global__ __launch_bounds__(256) void fuse_loss_kernel(
    const float* __restrict__ vis, const float* __restrict__ ir,
    const float* __restrict__ fus, const float* __restrict__ mask,
    float* __restrict__ ws, GaussW gw)
{
    __shared__ __align__(16) float4 s_u[1650];         // 26400 B union
    float2* s_av  = (float2*)s_u;                      // planes: av @0 (13440)
    float*  s_f   = (float*)((char*)s_u + 13440);      //         f  (6720)
    float2* s_hb  = (float2*)s_u;                      // h: hb @0 (10560)
    float2* s_hg  = (float2*)((char*)s_u + 10560);     //    hg (10560)
    float*  s_hqd = (float*)((char*)s_u + 21120);      //    hqd (5280)
    __shared__ float s_part[4];

    const int t  = threadIdx.x;
    const int cx = t & 31;
    const int r0 = t >> 5;           // 0..7

    float acc = 0.f;
    float lir[7], lvi[7], lfu[7], lmk[4];

    // ---- prologue: issue tile-0 loads (clamped addr, zeroed at store) ----
    {
        const int tile = blockIdx.x;
        const int rem  = tile & 255;
        const int y0 = (rem >> 4) * TH, x0 = (rem & 15) * TW;
        const size_t base = (size_t)(tile >> 8) * (size_t)(Hn * Wn);
        #pragma unroll
        for (int r = 0; r < 7; ++r) {
            int idx = t + 256 * r;
            int ry = idx / RW, rx = idx - ry * RW;
            int gy = y0 + ry - PADn, gx = x0 + rx - PADn;
            bool ok = (idx < NPTS) && ((unsigned)gy < (unsigned)Hn) &&
                      ((unsigned)gx < (unsigned)Wn);
            size_t o = ok ? (base + (size_t)gy * Wn + gx) : 0;
            lir[r] = ir[o]; lvi[r] = vis[o]; lfu[r] = fus[o];
        }
        const size_t mb = base + (size_t)(y0 + 4 * r0) * Wn + (x0 + cx);
        lmk[0] = mask[mb];          lmk[1] = mask[mb + Wn];
        lmk[2] = mask[mb + 2 * Wn]; lmk[3] = mask[mb + 3 * Wn];
    }

    #pragma unroll 1
    for (int it = 0; it < TPT; ++it) {
        const int tile = blockIdx.x + it * NBLK;
        const int rem  = tile & 255;
        const int y0 = (rem >> 4) * TH, x0 = (rem & 15) * TW;

        // ---- A: raw values -> planes (validity recomputed) ----
        #pragma unroll
        for (int r = 0; r < 7; ++r) {
            int idx = t + 256 * r;
            if (idx < NPTS) {
                int ry = idx / RW, rx = idx - ry * RW;
                int gy = y0 + ry - PADn, gx = x0 + rx - PADn;
                bool ok = ((unsigned)gy < (unsigned)Hn) &&
                          ((unsigned)gx < (unsigned)Wn);
                float a = ok ? lir[r] : 0.f;
                float v = ok ? lvi[r] : 0.f;
                float f = ok ? lfu[r] : 0.f;
                s_av[ry * PS + rx] = make_float2(a, v);
                s_f [ry * FS + rx] = f;
            }
        }
        float cm0 = lmk[0], cm1 = lmk[1], cm2 = lmk[2], cm3 = lmk[3];
        __syncthreads();                          // bar1: planes ready

        // ---- issue next tile's loads; in flight across B + C ----
        if (it + 1 < TPT) {
            const int nt = tile + NBLK;
            const int nrem = nt & 255;
            const int ny0 = (nrem >> 4) * TH, nx0 = (nrem & 15) * TW;
            const size_t nbase = (size_t)(nt >> 8) * (size_t)(Hn * Wn);
            #pragma unroll
            for (int r = 0; r < 7; ++r) {
                int idx = t + 256 * r;
                int ry = idx / RW, rx = idx - ry * RW;
                int gy = ny0 + ry - PADn, gx = nx0 + rx - PADn;
                bool ok = (idx < NPTS) && ((unsigned)gy < (unsigned)Hn) &&
                          ((unsigned)gx < (unsigned)Wn);
                size_t o = ok ? (nbase + (size_t)gy * Wn + gx) : 0;
                lir[r] = ir[o]; lvi[r] = vis[o]; lfu[r] = fus[o];
            }
            const size_t mb = nbase + (size_t)(ny0 + 4 * r0) * Wn + (nx0 + cx);
            lmk[0] = mask[mb];          lmk[1] = mask[mb + Wn];
            lmk[2] = mask[mb + 2 * Wn]; lmk[3] = mask[mb + 3 * Wn];
        }

        // ---- B: h into registers (reads planes) ----
        float hA[20], hB[20];
        do_task(t, gw, s_av, s_f, hA);
        if (t < 64) do_task(t + 256, gw, s_av, s_f, hB);
        __syncthreads();                          // bar2: plane reads done

        write_task(t, hA, s_hb, s_hg, s_hqd);     // h overwrites planes
        if (t < 64) write_task(t + 256, hB, s_hb, s_hg, s_hqd);
        __syncthreads();                          // bar3: h visible

        // ---- C: vertical pass, 4 consecutive rows/thread, 12 shared taps ----
        {
            float bi[4] = {0,0,0,0}, bv[4] = {0,0,0,0};
            float mi[4] = {0,0,0,0}, mv[4] = {0,0,0,0};
            float qd[4] = {0,0,0,0};
            #pragma unroll
            for (int j = 0; j < 12; ++j) {
                int row = 4 * r0 + j;
                float2 hb = s_hb[row * HS + cx];
                float2 hg = s_hg[row * HS + cx];
                float  hq = s_hqd[row * QS + cx];
                #pragma unroll
                for (int k = 0; k < 4; ++k) {
                    int d = j - k;
                    if (d >= 0 && d <= 8) {       // compile-time predicate
                        float gg = gw.g[d];
                        bi[k] += hb.x;  bv[k] += hb.y;
                        mi[k] = fmaf(gg, hg.x, mi[k]);
                        mv[k] = fmaf(gg, hg.y, mv[k]);
                        qd[k] = fmaf(gg, hq, qd[k]);
                    }
                }
            }
            #pragma unroll
            for (int k = 0; k < 4; ++k) {
                float dvar = qd[k] - (mi[k] - mv[k]) * (mi[k] + mv[k]);
                float m1  = (dvar > 0.f) ? 1.f : 0.f;
                float mkv = (k == 0) ? cm0 : (k == 1) ? cm1 : (k == 2) ? cm2 : cm3;
                float sel = (m1 + mkv > 0.f) ? 1.f : 0.f;
                acc += sel * (bi[k] * (1.f / 81.f)) +
                       (1.f - sel) * (bv[k] * (1.f / 81.f));
            }
        }
        __syncthreads();                          // bar4: h reads done before
                                                  // next A overwrites union
    }

    // ---- one partial per block, no atomics ----
    #pragma unroll
    for (int off = 32; off > 0; off >>= 1)
        acc += __shfl_down(acc, off, 64);
    int wave = t >> 6, lane = t & 63;
    if (lane == 0) s_part[wave] = acc;
    __syncthreads();
    if (t == 0)
        ws[blockIdx.x] = s_part[0] + s_part[1] + s_part[2] + s_part[3];
}

__global__ __launch_bounds__(256) void reduce_kernel(const float* __restrict__ ws,
                                                     float* __restrict__ out)
{
    __shared__ float sp[4];
    int t = threadIdx.x;
    float v = 0.f;
    for (int i = t; i < NBLK; i += 256) v += ws[i];
    #pragma unroll
    for (int off = 32; off > 0; off >>= 1)
        v += __shfl_down(v, off, 64);
    if ((t & 63) == 0) sp[t >> 6] = v;
    __syncthreads();
    if (t == 0)
        out[0] = (sp[0] + sp[1] + sp[2] + sp[3]) * (1.f / ((float)Bn * Hn * Wn));
}

extern "C" void kernel_launch(void* const* d_in, const int* in_sizes, int n_in,
                              void* d_out, int out_size, void* d_ws, size_t ws_size,
                              hipStream_t stream) {
    const float* vis  = (const float*)d_in[0];
    const float* ir   = (const float*)d_in[1];
    const float* fus  = (const float*)d_in[2];
    const float* mask = (const float*)d_in[3];
    float* out = (float*)d_out;
    float* ws  = (float*)d_ws;

    GaussW gw;
    double g[9], s = 0.0;
    for (int i = 0; i < 9; ++i) {
        int x = i - 4;
        g[i] = exp(-(double)(x * x) / 4.5);
        s += g[i];
    }
    for (int i = 0; i < 9; ++i) gw.g[i] = (float)(g[i] / s);

    fuse_loss_kernel<<<NBLK, 256, 0, stream>>>(vis, ir, fus, mask, ws, gw);
    reduce_kernel<<<1, 256, 0, stream>>>(ws, out);
}

// Round 16
// 68.429 us; speedup vs baseline: 1.0342x; 1.0342x over previous
//
#include <hip/hip_runtime.h>
#include <cmath>

#define Bn 32
#define Hn 512
#define Wn 512
#define PADn 4
#define TW 32
#define TH 32
#define RH 40
#define RW 40
#define PS 42          // av plane row stride (float2): even -> b128-aligned reads
#define FS 42          // f plane row stride (floats)
#define HS 33          // h-buffer row stride (float2 units)
#define NPTS (RH * RW)            // 1600
#define NTILES 8192
#define NBLK 768       // == 3 blocks/CU (LDS cap) x 256 CU: full residency, no tail

struct GaussW { float g[9]; };

// R16 = R14 (best: 61.8us) with the grid matched to the residency cap.
// R14 ran 1024 blocks against a 3-blocks/CU LDS cap -> 768 resident + a
// 256-block straggler tail at 1 block/CU (~1.33x T_block; 62/1.33 = 46us).
// NBLK=768 + grid-stride removes the tail. Single variable vs R14.
__global__ __launch_bounds__(256) void fuse_loss_kernel(
    const float* __restrict__ vis, const float* __restrict__ ir,
    const float* __restrict__ fus, const float* __restrict__ mask,
    float* __restrict__ ws, GaussW gw)
{
    __shared__ __align__(16) float2 s_av[RH * PS];   // (a, v)   13440 B
    __shared__ __align__(16) float  s_f [RH * FS];   // fuse      6720 B
    __shared__ float2 s_hb[RH * HS];                 // h box    10560 B
    __shared__ float2 s_hg[RH * HS];                 // h gauss  10560 B
    __shared__ float2 s_hq[RH * HS];                 // h gauss2 10560 B
    __shared__ float  s_part[4];                     // ~51.9 KB total

    const int t  = threadIdx.x;
    const int cx = t & 31;
    const int r0 = t >> 5;           // 0..7

    float acc = 0.f;
    float lir[7], lvi[7], lfu[7], lmk[4];

    // ---- prologue: issue tile-0 loads (clamped addr, zeroed at store) ----
    {
        const int tile = blockIdx.x;
        const int rem  = tile & 255;
        const int y0 = (rem >> 4) * TH, x0 = (rem & 15) * TW;
        const size_t base = (size_t)(tile >> 8) * (size_t)(Hn * Wn);
        #pragma unroll
        for (int r = 0; r < 7; ++r) {
            int idx = t + 256 * r;
            int ry = idx / RW, rx = idx - ry * RW;
            int gy = y0 + ry - PADn, gx = x0 + rx - PADn;
            bool ok = (idx < NPTS) && ((unsigned)gy < (unsigned)Hn) &&
                      ((unsigned)gx < (unsigned)Wn);
            size_t o = ok ? (base + (size_t)gy * Wn + gx) : 0;
            lir[r] = ir[o]; lvi[r] = vis[o]; lfu[r] = fus[o];
        }
        const size_t mb = base + (size_t)(y0 + 4 * r0) * Wn + (x0 + cx);
        lmk[0] = mask[mb];          lmk[1] = mask[mb + Wn];
        lmk[2] = mask[mb + 2 * Wn]; lmk[3] = mask[mb + 3 * Wn];
    }

    #pragma unroll 1
    for (int tile = blockIdx.x; tile < NTILES; tile += NBLK) {
        const int rem = tile & 255;
        const int y0 = (rem >> 4) * TH, x0 = (rem & 15) * TW;

        // ---- A': raw values -> planes (validity recomputed) ----
        #pragma unroll
        for (int r = 0; r < 7; ++r) {
            int idx = t + 256 * r;
            if (idx < NPTS) {
                int ry = idx / RW, rx = idx - ry * RW;
                int gy = y0 + ry - PADn, gx = x0 + rx - PADn;
                bool ok = ((unsigned)gy < (unsigned)Hn) &&
                          ((unsigned)gx < (unsigned)Wn);
                float a = ok ? lir[r] : 0.f;
                float v = ok ? lvi[r] : 0.f;
                float f = ok ? lfu[r] : 0.f;
                s_av[ry * PS + rx] = make_float2(a, v);
                s_f [ry * FS + rx] = f;
            }
        }
        float cm0 = lmk[0], cm1 = lmk[1], cm2 = lmk[2], cm3 = lmk[3];
        __syncthreads();                          // planes ready

        // ---- issue next tile's loads; in flight across B + C ----
        if (tile + NBLK < NTILES) {
            const int nt = tile + NBLK;
            const int nrem = nt & 255;
            const int ny0 = (nrem >> 4) * TH, nx0 = (nrem & 15) * TW;
            const size_t nbase = (size_t)(nt >> 8) * (size_t)(Hn * Wn);
            #pragma unroll
            for (int r = 0; r < 7; ++r) {
                int idx = t + 256 * r;
                int ry = idx / RW, rx = idx - ry * RW;
                int gy = ny0 + ry - PADn, gx = nx0 + rx - PADn;
                bool ok = (idx < NPTS) && ((unsigned)gy < (unsigned)Hn) &&
                          ((unsigned)gx < (unsigned)Wn);
                size_t o = ok ? (nbase + (size_t)gy * Wn + gx) : 0;
                lir[r] = ir[o]; lvi[r] = vis[o]; lfu[r] = fus[o];
            }
            const size_t mb = nbase + (size_t)(ny0 + 4 * r0) * Wn + (nx0 + cx);
            lmk[0] = mask[mb];          lmk[1] = mask[mb + Wn];
            lmk[2] = mask[mb + 2 * Wn]; lmk[3] = mask[mb + 3 * Wn];
        }

        // ---- B: horizontal pass, 4 adjacent cols per task ----
        #pragma unroll 1
        for (int task = t; task < 320; task += 256) {
            int ry = task >> 3, g = task & 7;
            int po = ry * PS + 4 * g;             // float2 idx, even
            int ho = ry * HS + 4 * g;

            float2 av[12];
            #pragma unroll
            for (int j = 0; j < 6; ++j)
                *(float4*)&av[2 * j] = *(const float4*)&s_av[po + 2 * j];
            float2 fv[6];
            {
                const float2* fp = (const float2*)s_f;
                int fo2 = (ry * FS + 4 * g) >> 1; // FS even, 4g even
                #pragma unroll
                for (int j = 0; j < 6; ++j) fv[j] = fp[fo2 + j];
            }

            {   // box: d^2 then sliding 9-wide sum
                float dI[12], dV[12];
                #pragma unroll
                for (int k = 0; k < 12; ++k) {
                    float f = (k & 1) ? fv[k >> 1].y : fv[k >> 1].x;
                    float di = av[k].x - f, dv = av[k].y - f;
                    dI[k] = di * di; dV[k] = dv * dv;
                }
                float si = ((dI[0] + dI[1]) + (dI[2] + dI[3])) +
                           ((dI[4] + dI[5]) + (dI[6] + dI[7])) + dI[8];
                float sv = ((dV[0] + dV[1]) + (dV[2] + dV[3])) +
                           ((dV[4] + dV[5]) + (dV[6] + dV[7])) + dV[8];
                s_hb[ho + 0] = make_float2(si, sv);
                si += dI[9]  - dI[0];  sv += dV[9]  - dV[0];
                s_hb[ho + 1] = make_float2(si, sv);
                si += dI[10] - dI[1];  sv += dV[10] - dV[1];
                s_hb[ho + 2] = make_float2(si, sv);
                si += dI[11] - dI[2];  sv += dV[11] - dV[2];
                s_hb[ho + 3] = make_float2(si, sv);
            }
            {   // gauss on (a,v) and (a^2,v^2)
                float sqI[12], sqV[12];
                #pragma unroll
                for (int k = 0; k < 12; ++k) {
                    sqI[k] = av[k].x * av[k].x;
                    sqV[k] = av[k].y * av[k].y;
                }
                #pragma unroll
                for (int m = 0; m < 4; ++m) {
                    float ga = 0.f, gv = 0.f, qa = 0.f, qv = 0.f;
                    #pragma unroll
                    for (int dx = 0; dx < 9; ++dx) {
                        float gg = gw.g[dx];
                        ga = fmaf(gg, av[m + dx].x, ga);
                        gv = fmaf(gg, av[m + dx].y, gv);
                        qa = fmaf(gg, sqI[m + dx], qa);
                        qv = fmaf(gg, sqV[m + dx], qv);
                    }
                    s_hg[ho + m] = make_float2(ga, gv);
                    s_hq[ho + m] = make_float2(qa, qv);
                }
            }
        }
        __syncthreads();                          // h ready

        // ---- C: vertical pass, 4 consecutive rows/thread, 12 shared taps ----
        {
            float bi[4] = {0,0,0,0}, bv[4] = {0,0,0,0};
            float mi[4] = {0,0,0,0}, mv[4] = {0,0,0,0};
            float qi[4] = {0,0,0,0}, qv[4] = {0,0,0,0};
            #pragma unroll
            for (int j = 0; j < 12; ++j) {
                int off = (4 * r0 + j) * HS + cx;
                float2 hb = s_hb[off];
                float2 hg = s_hg[off];
                float2 hq = s_hq[off];
                #pragma unroll
                for (int k = 0; k < 4; ++k) {
                    int d = j - k;
                    if (d >= 0 && d <= 8) {       // compile-time predicate
                        float gg = gw.g[d];
                        bi[k] += hb.x;  bv[k] += hb.y;
                        mi[k] = fmaf(gg, hg.x, mi[k]);
                        mv[k] = fmaf(gg, hg.y, mv[k]);
                        qi[k] = fmaf(gg, hq.x, qi[k]);
                        qv[k] = fmaf(gg, hq.y, qv[k]);
                    }
                }
            }
            #pragma unroll
            for (int k = 0; k < 4; ++k) {
                float var_i = qi[k] - mi[k] * mi[k];
                float var_v = qv[k] - mv[k] * mv[k];
                float m1  = (var_i - var_v > 0.f) ? 1.f : 0.f;
                float mkv = (k == 0) ? cm0 : (k == 1) ? cm1 : (k == 2) ? cm2 : cm3;
                float sel = (m1 + mkv > 0.f) ? 1.f : 0.f;
                acc += sel * (bi[k] * (1.f / 81.f)) +
                       (1.f - sel) * (bv[k] * (1.f / 81.f));
            }
        }
        // no 3rd barrier: next A' writes planes (disjoint from h-buffers
        // read by C); next B is ordered behind next bar1.
    }

    // ---- one partial per block, no atomics ----
    #pragma unroll
    for (int off = 32; off > 0; off >>= 1)
        acc += __shfl_down(acc, off, 64);
    int wave = t >> 6, lane = t & 63;
    if (lane == 0) s_part[wave] = acc;
    __syncthreads();
    if (t == 0)
        ws[blockIdx.x] = s_part[0] + s_part[1] + s_part[2] + s_part[3];
}

__global__ __launch_bounds__(256) void reduce_kernel(const float* __restrict__ ws,
                                                     float* __restrict__ out)
{
    __shared__ float sp[4];
    int t = threadIdx.x;
    float v = 0.f;
    for (int i = t; i < NBLK; i += 256) v += ws[i];
    #pragma unroll
    for (int off = 32; off > 0; off >>= 1)
        v += __shfl_down(v, off, 64);
    if ((t & 63) == 0) sp[t >> 6] = v;
    __syncthreads();
    if (t == 0)
        out[0] = (sp[0] + sp[1] + sp[2] + sp[3]) * (1.f / ((float)Bn * Hn * Wn));
}

extern "C" void kernel_launch(void* const* d_in, const int* in_sizes, int n_in,
                              void* d_out, int out_size, void* d_ws, size_t ws_size,
                              hipStream_t stream) {
    const float* vis  = (const float*)d_in[0];
    const float* ir   = (const float*)d_in[1];
    const float* fus  = (const float*)d_in[2];
    const float* mask = (const float*)d_in[3];
    float* out = (float*)d_out;
    float* ws  = (float*)d_ws;

    GaussW gw;
    double g[9], s = 0.0;
    for (int i = 0; i < 9; ++i) {
        int x = i - 4;
        g[i] = exp(-(double)(x * x) / 4.5);
        s += g[i];
    }
    for (int i = 0; i < 9; ++i) gw.g[i] = (float)(g[i] / s);

    fuse_loss_kernel<<<NBLK, 256, 0, stream>>>(vis, ir, fus, mask, ws, gw);
    reduce_kernel<<<1, 256, 0, stream>>>(ws, out);
}

// Round 20
// 42.689 us; speedup vs baseline: 1.6579x; 1.6030x over previous
//
#include <hip/hip_runtime.h>
#include <cmath>

#define Hn 512
#define Wn 512
#define Bn 32
#define BANDS 16
#define BH 32                       // output rows per band
#define NBLK (Bn * BANDS)           // 512 blocks
#define NT 512                      // 1 thread per column

struct GaussW { float g[9]; };

__device__ __forceinline__ void load_row(
    const float* __restrict__ pir, const float* __restrict__ pvi,
    const float* __restrict__ pfu, int y, int x,
    float& a, float& v, float& f)
{
    bool ok = (unsigned)y < (unsigned)Hn;
    size_t o = ok ? ((size_t)y * Wn + x) : 0;
    float aa = pir[o], vv = pvi[o], ff = pfu[o];
    a = ok ? aa : 0.f;  v = ok ? vv : 0.f;  f = ok ? ff : 0.f;
}

__device__ __forceinline__ void stage_row(
    float4* rowq, float* rowpd, int x, float a, float v, float f)
{
    float di = a - f, dv = v - f;
    rowq [x + 4] = make_float4(a, v, di * di, dv * dv);
    rowpd[x + 4] = (a - v) * (a + v);          // a^2 - v^2
}

// one image row: horizontal 9-tap from LDS + in-register vertical update.
// j, emit are compile-time constants after full unroll (rule #20).
__device__ __forceinline__ void compute_row(
    const float4* rowq, const float* rowpd, int x, int j, bool emit,
    float mk, const GaussW& gw,
    float* hb_i, float* hb_v, float* ag_i, float* ag_v, float* ag_q,
    float& Sbi, float& Sbv, float& acc)
{
    float bi = 0.f, bv = 0.f, ga = 0.f, gv = 0.f, qd = 0.f;
    #pragma unroll
    for (int i = 0; i < 9; ++i) {
        float4 q = rowq[x + i];
        float pd = rowpd[x + i];
        float gg = gw.g[i];
        bi += q.z;  bv += q.w;
        ga = fmaf(gg, q.x, ga);
        gv = fmaf(gg, q.y, gv);
        qd = fmaf(gg, pd, qd);
    }
    // vertical box: telescoping 9-row window
    Sbi += bi - hb_i[j];  hb_i[j] = bi;
    Sbv += bv - hb_v[j];  hb_v[j] = bv;
    // vertical gauss: 9 phase-rotating slots (R6-verified weights)
    float mi = 0.f, mv = 0.f, mq = 0.f;
    const float g8 = gw.g[8];
    #pragma unroll
    for (int s = 0; s < 9; ++s) {
        if (s == j) {
            mi = fmaf(g8, ga, ag_i[j]);
            mv = fmaf(g8, gv, ag_v[j]);
            mq = fmaf(g8, qd, ag_q[j]);
        } else {
            float w = gw.g[(j - s - 1 + 9) % 9];
            ag_i[s] = fmaf(w, ga, ag_i[s]);
            ag_v[s] = fmaf(w, gv, ag_v[s]);
            ag_q[s] = fmaf(w, qd, ag_q[s]);
        }
    }
    ag_i[j] = 0.f; ag_v[j] = 0.f; ag_q[j] = 0.f;
    if (emit) {
        float dvar = mq - (mi - mv) * (mi + mv);   // var_i - var_v (R15-verified)
        float m1  = (dvar > 0.f) ? 1.f : 0.f;
        float sel = (m1 + mk > 0.f) ? 1.f : 0.f;
        acc += sel * (Sbi * (1.f / 81.f)) + (1.f - sel) * (Sbv * (1.f / 81.f));
    }
}

// R17: row-marching band kernel. 512 threads = 512 columns; march 40 rows
// (32 outputs + 8 halo). Stage derived values once per source px into a
// 2-row dbuf LDS ring; vertical passes live in registers (box telescope +
// 9-slot gauss rotation). 1 barrier per 2 rows. Full unroll keeps every
// hist/slot index static.
__global__ __launch_bounds__(NT) void fuse_loss_kernel(
    const float* __restrict__ vis, const float* __restrict__ ir,
    const float* __restrict__ fus, const float* __restrict__ mask,
    float* __restrict__ ws, GaussW gw)
{
    __shared__ __align__(16) float4 s_q [2][2][Wn + 8];   // (a,v,d2i,d2v) 33280 B
    __shared__ float  s_pd[2][2][Wn + 8];                 // a^2-v^2        8320 B
    __shared__ float  s_part[8];

    const int t    = threadIdx.x;                 // column x
    const int img  = blockIdx.x >> 4;
    const int band = blockIdx.x & 15;
    const int Y0   = band * BH;
    const size_t ibase = (size_t)img * (size_t)(Hn * Wn);
    const float* pir = ir  + ibase;
    const float* pvi = vis + ibase;
    const float* pfu = fus + ibase;
    const float* pmk = mask + ibase;

    // zero the 4-px horizontal halos once (stage never touches them)
    if (t < 32) {
        int b = (t >> 4) & 1, rr = (t >> 3) & 1, e = t & 7;
        int col = (e < 4) ? e : (Wn + e);         // 0..3, 516..519
        s_q [b][rr][col] = make_float4(0.f, 0.f, 0.f, 0.f);
        s_pd[b][rr][col] = 0.f;
    }

    // vertical state (all statically indexed after unroll)
    float hb_i[9], hb_v[9], ag_i[9], ag_v[9], ag_q[9];
    #pragma unroll
    for (int s = 0; s < 9; ++s) {
        hb_i[s] = 0.f; hb_v[s] = 0.f;
        ag_i[s] = 0.f; ag_v[s] = 0.f; ag_q[s] = 0.f;
    }
    float Sbi = 0.f, Sbv = 0.f, acc = 0.f;

    // prologue: rows r=0,1 -> buf0; issue loads for rows r=2,3
    float aA, vA, fA, aB, vB, fB;
    load_row(pir, pvi, pfu, Y0 - 4, t, aA, vA, fA);
    load_row(pir, pvi, pfu, Y0 - 3, t, aB, vB, fB);
    stage_row(s_q[0][0], s_pd[0][0], t, aA, vA, fA);
    stage_row(s_q[0][1], s_pd[0][1], t, aB, vB, fB);
    load_row(pir, pvi, pfu, Y0 - 2, t, aA, vA, fA);
    load_row(pir, pvi, pfu, Y0 - 1, t, aB, vB, fB);
    float mkA = 0.f, mkB = 0.f;
    __syncthreads();

    #pragma unroll
    for (int p = 0; p < 20; ++p) {
        const int cur = p & 1;
        // stage rows 2p+2, 2p+3 (preloaded last iter) into the other buffer
        if (p < 19) {
            stage_row(s_q[cur ^ 1][0], s_pd[cur ^ 1][0], t, aA, vA, fA);
            stage_row(s_q[cur ^ 1][1], s_pd[cur ^ 1][1], t, aB, vB, fB);
        }
        // issue loads for rows 2p+4, 2p+5 (consumed next iter)
        if (p < 18) {
            load_row(pir, pvi, pfu, Y0 + 2 * p,     t, aA, vA, fA);
            load_row(pir, pvi, pfu, Y0 + 2 * p + 1, t, aB, vB, fB);
        }
        // compute rows r=2p, 2p+1 from buf[cur]; emit when r>=8
        compute_row(s_q[cur][0], s_pd[cur][0], t, (2 * p) % 9,  (p >= 4),
                    mkA, gw, hb_i, hb_v, ag_i, ag_v, ag_q, Sbi, Sbv, acc);
        compute_row(s_q[cur][1], s_pd[cur][1], t, (2 * p + 1) % 9, (p >= 4),
                    mkB, gw, hb_i, hb_v, ag_i, ag_v, ag_q, Sbi, Sbv, acc);
        // issue mask loads for pair p+1's emit rows
        if (p >= 3 && p < 19) {
            mkA = pmk[(size_t)(Y0 + 2 * p - 6) * Wn + t];
            mkB = pmk[(size_t)(Y0 + 2 * p - 5) * Wn + t];
        }
        __syncthreads();
    }

    // block reduction -> one partial per block
    #pragma unroll
    for (int off = 32; off > 0; off >>= 1)
        acc += __shfl_down(acc, off, 64);
    if ((t & 63) == 0) s_part[t >> 6] = acc;
    __syncthreads();
    if (t == 0) {
        float s = 0.f;
        #pragma unroll
        for (int i = 0; i < 8; ++i) s += s_part[i];
        ws[blockIdx.x] = s;
    }
}

__global__ __launch_bounds__(256) void reduce_kernel(const float* __restrict__ ws,
                                                     float* __restrict__ out)
{
    __shared__ float sp[4];
    int t = threadIdx.x;
    float v = 0.f;
    for (int i = t; i < NBLK; i += 256) v += ws[i];
    #pragma unroll
    for (int off = 32; off > 0; off >>= 1)
        v += __shfl_down(v, off, 64);
    if ((t & 63) == 0) sp[t >> 6] = v;
    __syncthreads();
    if (t == 0)
        out[0] = (sp[0] + sp[1] + sp[2] + sp[3]) * (1.f / ((float)Bn * Hn * Wn));
}

extern "C" void kernel_launch(void* const* d_in, const int* in_sizes, int n_in,
                              void* d_out, int out_size, void* d_ws, size_t ws_size,
                              hipStream_t stream) {
    const float* vis  = (const float*)d_in[0];
    const float* ir   = (const float*)d_in[1];
    const float* fus  = (const float*)d_in[2];
    const float* mask = (const float*)d_in[3];
    float* out = (float*)d_out;
    float* ws  = (float*)d_ws;

    GaussW gw;
    double g[9], s = 0.0;
    for (int i = 0; i < 9; ++i) {
        int x = i - 4;
        g[i] = exp(-(double)(x * x) / 4.5);
        s += g[i];
    }
    for (int i = 0; i < 9; ++i) gw.g[i] = (float)(g[i] / s);

    fuse_loss_kernel<<<NBLK, NT, 0, stream>>>(vis, ir, fus, mask, ws, gw);
    reduce_kernel<<<1, 256, 0, stream>>>(ws, out);
}